// Round 5
// baseline (10934.164 us; speedup 1.0000x reference)
//
#include <hip/hip_runtime.h>
#include <stdint.h>

#define LOG2E_F 1.4426950408889634f
#define LN2_D   0.6931471805599453
#define SEQLEN 16384
#define NTAGS  1024
#define NSEG   8
#define SEGLEN (SEQLEN / NSEG)   // 2048
#define NREC   (2 * NSEG)        // 16 recurrences (8 fwd + 8 bwd)
#define BPR    16                // blocks per recurrence
#define TPB    512
#define ROWS   64                // rows per block
#define ELDS_BYTES 131072        // 64 rows x 512 u32 (bf16-pair-packed exp(T))
#define GUARD_MAX 500000

// ---- ws layout (bytes) ----
// 0      : wbufs [16][2][1024] u32   (double-buffered packed words: (bf16<<16)|tag)
// 131072 : rm2  [16384] f32
// 196608 : part [16][1024] f32
// 262144 : Ssum [16] double
// 262272 : fs f32 ; 262276 : tsum f32

__device__ __forceinline__ uint32_t bf16rne(float x) {
    uint32_t b = __float_as_uint(x);
    b += 0x7FFFu + ((b >> 16) & 1u);
    return b;   // caller takes >>16 (low slot) or &0xFFFF0000 (high slot)
}

__global__ void crf_clear_k(uint32_t* __restrict__ wbufs) {
    const int tid = threadIdx.x;
    for (int i = tid; i < NREC * 2 * NTAGS; i += 256)
        __hip_atomic_store(&wbufs[i], 0xFFFFu, __ATOMIC_RELAXED, __HIP_MEMORY_SCOPE_AGENT);
}

__global__ void crf_rowmax_k(const float* __restrict__ feats, float* __restrict__ rm2) {
    const int t = blockIdx.x;
    const int tid = threadIdx.x; // 256
    const float* row = feats + (size_t)t * NTAGS;
    float m = row[tid];
    m = fmaxf(m, row[tid + 256]);
    m = fmaxf(m, row[tid + 512]);
    m = fmaxf(m, row[tid + 768]);
    for (int off = 32; off > 0; off >>= 1) m = fmaxf(m, __shfl_xor(m, off));
    __shared__ float sm[4];
    if ((tid & 63) == 0) sm[tid >> 6] = m;
    __syncthreads();
    if (tid == 0) rm2[t] = fmaxf(fmaxf(sm[0], sm[1]), fmaxf(sm[2], sm[3])) * LOG2E_F;
}

__global__ void crf_emit_k(const float* __restrict__ feats, const int* __restrict__ tags,
                           float* __restrict__ part) {
    __shared__ int tg[1024];
    const int tid = threadIdx.x;          // 256
    const int b = blockIdx.x;             // 64 blocks: 16 t-chunks x 4 col-chunks
    const int cch = b >> 2;
    const int jb = b & 3;
    for (int q = tid; q < 1024; q += 256) tg[q] = tags[cch * 1024 + q];
    __syncthreads();
    const int j = jb * 256 + tid;
    float acc = 0.f;
#pragma unroll 8
    for (int k = 0; k < 1024; ++k) acc += feats[(size_t)tg[k] * NTAGS + j];
    part[cch * NTAGS + j] = acc;          // deterministic fixed-order partials
}

__global__ void crf_trans_k(const float* __restrict__ trans, const int* __restrict__ tags,
                            const int* __restrict__ start_p, float* __restrict__ tsum) {
    __shared__ float red[256];
    const int tid = threadIdx.x;
    const int start = *start_p;
    float acc = 0.f;
    for (int k = 0; k < 64; ++k) {
        const int t = tid * 64 + k;
        const int prev = (t == 0) ? start : tags[t - 1];
        acc += trans[(size_t)tags[t] * NTAGS + prev];
    }
    red[tid] = acc;
    __syncthreads();
    for (int s = 128; s > 0; s >>= 1) { if (tid < s) red[tid] += red[tid + s]; __syncthreads(); }
    if (tid == 0) *tsum = red[0];
}

__global__ __launch_bounds__(TPB, 1) void crf_scan_k(
    const float* __restrict__ feats, const float* __restrict__ trans,
    uint32_t* __restrict__ wbufs, const float* __restrict__ rm2,
    double* __restrict__ Ssum)
{
    extern __shared__ uint32_t elds[];      // [64][512] u32: swizzled bf16-pair exp(T)
    __shared__ float w_lds[8 * 132];        // stride 132: conflict-free float4 reads
    __shared__ float wmax_lds[8];
    __shared__ int deadf;

    const int tid = threadIdx.x;
    const int rec = blockIdx.x & (NREC - 1);
    const int rank = blockIdx.x >> 4;       // 0..15
    const int seg = rec & (NSEG - 1);
    const int bwd = rec >> 3;               // 0 = forward, 1 = backward (transpose)
    const int a = seg * SEGLEN;
    const int r = tid >> 3;                 // row-in-block 0..63
    const int c = tid & 7;                  // 128-col chunk 0..7
    const int row = rank * ROWS + r;        // global state index
    const bool c0 = (c == 0);
    uint32_t* wbuf = wbufs + rec * (2 * NTAGS);

    // ---- stage E chunk into LDS as bf16 pairs, +4c u32-swizzle per c-chunk ----
    // fwd: E[row, c*128+k] = exp(T[row, c*128+k]); bwd: exp(T[c*128+k, row]).
    {
        const size_t estride = bwd ? (size_t)NTAGS : 1;
        const float* tp = bwd ? (trans + (size_t)(c * 128) * NTAGS + row)
                              : (trans + (size_t)row * NTAGS + c * 128);
        uint32_t* erow = elds + r * 512 + c * 64;
#pragma unroll 8
        for (int m = 0; m < 64; ++m) {      // pair m = cols {2m, 2m+1} of this chunk
            const float a0 = exp2f(tp[(size_t)(2 * m) * estride] * LOG2E_F);
            const float a1 = exp2f(tp[(size_t)(2 * m + 1) * estride] * LOG2E_F);
            erow[(m + 4 * c) & 63] = (bf16rne(a0) >> 16) | (bf16rne(a1) & 0xFFFF0000u);
        }
    }
    if (tid == 0) deadf = 0;

    // Initial publish (tag 0). fwd: uniform ones. bwd: D_{last}*1 scaled by 2^-C0.
    double S = 0.0;
    if (!bwd) {
        if (c0)
            __hip_atomic_store(&wbuf[row], __float_as_uint(1.0f) & 0xFFFF0000u,
                               __ATOMIC_RELAXED, __HIP_MEMORY_SCOPE_AGENT);
    } else {
        const float C0 = rm2[a + SEGLEN - 1] + 10.0f;
        S = (double)C0;
        if (c0) {
            const float fL = feats[(size_t)(a + SEGLEN - 1) * NTAGS + row] * LOG2E_F;
            __hip_atomic_store(&wbuf[row], bf16rne(exp2f(fL - C0)) & 0xFFFF0000u,
                               __ATOMIC_RELAXED, __HIP_MEMORY_SCOPE_AGENT);
        }
    }
    __syncthreads();   // elds staged, init published, deadf visible

    // feat index applied at publish of tag k+1:
    //   fwd: a+k ; bwd: (a+SEGLEN-2)-k while k <= SEGLEN-2 (final publish has no D)
    float featL_cur = 0.f, rm2_cur = 0.f;
    {
        const int f0 = bwd ? (a + SEGLEN - 2) : a;
        rm2_cur = rm2[f0];
        if (c0) featL_cur = feats[(size_t)f0 * NTAGS + row] * LOG2E_F;
    }

    const int i0 = tid * 2;
    const int sidx = (i0 >> 7) * 132 + (i0 & 127);
    const uint32_t* ew = elds + r * 512 + c * 64;
    const float* wl = &w_lds[c * 132];

    for (int k = 0; k < SEGLEN; ++k) {
        const uint32_t tag = (uint32_t)k;
        const uint64_t tag2 = (uint64_t)tag | ((uint64_t)tag << 32);
        uint32_t* wb = wbuf + (k & 1) * NTAGS;

        // prefetch next step's feat/rm2 (issues before the poll; waits at use)
        float featL_nxt = 0.f, rm2_nxt = 0.f;
        {
            const int kn = k + 1;
            int fn = -1;
            if (kn < SEGLEN) fn = bwd ? ((kn <= SEGLEN - 2) ? (a + SEGLEN - 2 - kn) : -1)
                                      : (a + kn);
            if (fn >= 0) {
                rm2_nxt = rm2[fn];
                if (c0) featL_nxt = feats[(size_t)fn * NTAGS + row] * LOG2E_F;
            }
        }

        // ---- poll my two packed words as one 8B load; s_sleep backoff ----
        uint32_t wa, wv;
        {
            int guard = 0;
            for (;;) {
                const uint64_t v = __hip_atomic_load((const uint64_t*)&wb[i0],
                                                     __ATOMIC_RELAXED,
                                                     __HIP_MEMORY_SCOPE_AGENT);
                if ((((v ^ tag2)) & 0x0000FFFF0000FFFFull) == 0ull) {
                    wa = (uint32_t)v; wv = (uint32_t)(v >> 32); break;
                }
                if (++guard > GUARD_MAX) { deadf = 1; wa = wv = 0; break; }
                __builtin_amdgcn_s_sleep(1);
            }
        }
        __syncthreads();               // prev-iter LDS reads complete; deadf visible
        if (deadf) break;              // uniform abort (no hang)

        const float w0f = __uint_as_float(wa & 0xFFFF0000u);
        const float w1f = __uint_as_float(wv & 0xFFFF0000u);
        w_lds[sidx] = w0f; w_lds[sidx + 1] = w1f;
        float m2 = fmaxf(w0f, w1f);
#pragma unroll
        for (int o = 32; o > 0; o >>= 1) m2 = fmaxf(m2, __shfl_xor(m2, o));
        if ((tid & 63) == 0) wmax_lds[tid >> 6] = m2;
        __syncthreads();

        float mw = wmax_lds[0];
#pragma unroll
        for (int q = 1; q < 8; ++q) mw = fmaxf(mw, wmax_lds[q]);
        const float C = rm2_cur + __log2f(mw) + 10.0f;  // identical in every block
        S += (double)C;

        // d_row partial: LDS bf16-pair E x LDS f32 w
        float acc = 0.f;
#pragma unroll
        for (int q = 0; q < 16; ++q) {
            const uint4 e4 = *(const uint4*)&ew[(4 * q + 4 * c) & 63];
            const float4 wA = *(const float4*)&wl[8 * q];
            const float4 wB = *(const float4*)&wl[8 * q + 4];
            acc = fmaf(__uint_as_float(e4.x << 16),          wA.x, acc);
            acc = fmaf(__uint_as_float(e4.x & 0xFFFF0000u),  wA.y, acc);
            acc = fmaf(__uint_as_float(e4.y << 16),          wA.z, acc);
            acc = fmaf(__uint_as_float(e4.y & 0xFFFF0000u),  wA.w, acc);
            acc = fmaf(__uint_as_float(e4.z << 16),          wB.x, acc);
            acc = fmaf(__uint_as_float(e4.z & 0xFFFF0000u),  wB.y, acc);
            acc = fmaf(__uint_as_float(e4.w << 16),          wB.z, acc);
            acc = fmaf(__uint_as_float(e4.w & 0xFFFF0000u),  wB.w, acc);
        }
        acc += __shfl_xor(acc, 4);
        acc += __shfl_xor(acc, 2);
        acc += __shfl_xor(acc, 1);     // 8 lanes of a row -> full dot product

        if (c0) {
            const float wn = acc * exp2f(featL_cur - C);
            __hip_atomic_store(&wbuf[((k + 1) & 1) * NTAGS + row],
                               (bf16rne(wn) & 0xFFFF0000u) | ((tag + 1u) & 0xFFFFu),
                               __ATOMIC_RELAXED, __HIP_MEMORY_SCOPE_AGENT);
        }
        featL_cur = featL_nxt; rm2_cur = rm2_nxt;
    }

    if (rank == 0 && tid == 0) Ssum[rec] = S;
}

// Serial stitch: v0 = init; for s: c = LSE(z_s+v)-LSE(z_s); v = y_s + c.
__global__ void crf_stitch_k(const uint32_t* __restrict__ wbufs,
                             const double* __restrict__ Ssum,
                             const float* __restrict__ trans,
                             const int* __restrict__ start_p, const int* __restrict__ stop_p,
                             float* __restrict__ fs_out)
{
    const int j = threadIdx.x;   // 1024
    __shared__ float sred[16];

    auto bmax = [&](float x) -> float {
#pragma unroll
        for (int o = 32; o > 0; o >>= 1) x = fmaxf(x, __shfl_xor(x, o));
        if ((j & 63) == 0) sred[j >> 6] = x;
        __syncthreads();
        float m = sred[0];
#pragma unroll
        for (int q = 1; q < 16; ++q) m = fmaxf(m, sred[q]);
        __syncthreads();
        return m;
    };
    auto bsum = [&](float x) -> float {
#pragma unroll
        for (int o = 32; o > 0; o >>= 1) x += __shfl_xor(x, o);
        if ((j & 63) == 0) sred[j >> 6] = x;
        __syncthreads();
        float s = 0.f;
#pragma unroll
        for (int q = 0; q < 16; ++q) s += sred[q];
        __syncthreads();
        return s;
    };

    float v = (j == *start_p) ? 0.0f : -10000.0f;
    for (int s = 0; s < NSEG; ++s) {
        const float yp = __uint_as_float(wbufs[s * 2048 + j] & 0xFFFF0000u);
        const float zp = __uint_as_float(wbufs[(NSEG + s) * 2048 + j] & 0xFFFF0000u);
        const float y = (float)(LN2_D * ((double)__log2f(yp) + Ssum[s]));
        const float z = (float)(LN2_D * ((double)__log2f(zp) + Ssum[NSEG + s]));
        const float m1 = bmax(z + v);
        const float s1 = bsum(__expf(z + v - m1));
        const float m2 = bmax(z);
        const float s2 = bsum(__expf(z - m2));
        v = y + ((m1 + __logf(s1)) - (m2 + __logf(s2)));
    }
    const float tr = trans[(size_t)(*stop_p) * NTAGS + j];
    const float m = bmax(v + tr);
    const float ss = bsum(__expf(v + tr - m));
    if (j == 0) fs_out[0] = m + __logf(ss);
}

__global__ void crf_out_k(const float* __restrict__ fsp, const float* __restrict__ tsum,
                          const float* __restrict__ part, const float* __restrict__ trans,
                          const int* __restrict__ tags, const int* __restrict__ stop_p,
                          float* __restrict__ out) {
    const int j = threadIdx.x; // 1024
    float e = 0.f;
    for (int cc = 0; cc < 16; ++cc) e += part[cc * NTAGS + j];
    const int stop = *stop_p;
    const int last = tags[SEQLEN - 1];
    out[j] = fsp[0] - (tsum[0] + e + trans[(size_t)stop * NTAGS + last]);
}

extern "C" void kernel_launch(void* const* d_in, const int* in_sizes, int n_in,
                              void* d_out, int out_size, void* d_ws, size_t ws_size,
                              hipStream_t stream) {
    const float* feats = (const float*)d_in[0];
    const float* trans = (const float*)d_in[1];
    const int* tags    = (const int*)d_in[2];
    const int* start_p = (const int*)d_in[3];
    const int* stop_p  = (const int*)d_in[4];
    float* out = (float*)d_out;

    char* ws = (char*)d_ws;
    uint32_t* wbufs = (uint32_t*)(ws + 0);
    float* rm2      = (float*)(ws + 131072);
    float* part     = (float*)(ws + 196608);
    double* Ssum    = (double*)(ws + 262144);
    float* fs       = (float*)(ws + 262272);
    float* tsum     = (float*)(ws + 262276);

    (void)hipFuncSetAttribute((const void*)crf_scan_k,
                              hipFuncAttributeMaxDynamicSharedMemorySize, ELDS_BYTES);

    crf_clear_k<<<1, 256, 0, stream>>>(wbufs);
    crf_rowmax_k<<<SEQLEN, 256, 0, stream>>>(feats, rm2);
    crf_emit_k<<<64, 256, 0, stream>>>(feats, tags, part);
    crf_trans_k<<<1, 256, 0, stream>>>(trans, tags, start_p, tsum);
    crf_scan_k<<<NREC * BPR, TPB, ELDS_BYTES, stream>>>(feats, trans, wbufs, rm2, Ssum);
    crf_stitch_k<<<1, 1024, 0, stream>>>(wbufs, Ssum, trans, start_p, stop_p, fs);
    crf_out_k<<<1, 1024, 0, stream>>>(fs, tsum, part, trans, tags, stop_p, out);
}